// Round 5
// baseline (399.792 us; speedup 1.0000x reference)
//
#include <hip/hip_runtime.h>
#include <hip/hip_bf16.h>
#include <hip/hip_cooperative_groups.h>

namespace cg = cooperative_groups;

#define H_DIM 512
#define N_HEADS 8
#define HEAD_DIM 64
#define NBATCH 16

typedef __attribute__((ext_vector_type(8))) short short8;   // 8 bf16 (4 VGPRs)
typedef __attribute__((ext_vector_type(4))) float floatx4;  // MFMA acc

typedef unsigned short us16;

// 3-bit row swizzle for XOR'd LDS slots (structurally conflict-free b128)
#define SW3(r) ((((r) >> 1) & 3) | (((r) & 1) << 2))

// head-major channel permutation: c (=d*8+h) -> c' (=h*64+d)
#define PERMC(c) ((((c) & 7) << 6) | ((c) >> 3))
// inverse: c' -> c
#define IPERMC(cp) ((((cp) & 63) << 3) | ((cp) >> 6))

__device__ inline unsigned short f2bf(float f) {
  unsigned int u = __float_as_uint(f);
  unsigned int r = (u + 0x7fffu + ((u >> 16) & 1u)) >> 16;  // RNE
  return (unsigned short)r;
}

// async global->LDS, 16B/lane; lds dest = wave-uniform base + lane*16
__device__ inline void gld16(const us16* g, us16* l) {
  __builtin_amdgcn_global_load_lds(
      (const __attribute__((address_space(1))) void*)g,
      (__attribute__((address_space(3))) void*)l, 16, 0, 0);
}

// ---------------------------------------------------------------------------
// prep_all: one dispatch for (a) all fp32->bf16 casts + BN-stat zero
// [blocks 0..2047], (b) Wc = W1b @ Wm weight composite [blocks 2048..2111],
// (c) b1p = b1 + W1b @ bm [blocks 2112..2113]. All three are independent.
// Wq/Wk rows are PERMUTED to head-major (c' = PERMC(c)) so the QKV GEMM
// epilogue writes plain row-major [M][512] coalesced. Wv stays original
// (V keeps its plane layout). Wc's k-columns are permuted to match the
// head-major attention output Ob.
// ---------------------------------------------------------------------------
__global__ __launch_bounds__(256) void prep_all(
    const float* __restrict__ src_h, const float* __restrict__ dst_h,
    const float* __restrict__ Wq, const float* __restrict__ Wk,
    const float* __restrict__ Wv, const float* __restrict__ W1,
    const float* __restrict__ W2, const float* __restrict__ Wm,
    const float* __restrict__ b1, const float* __restrict__ bm,
    us16* __restrict__ src_bf, us16* __restrict__ dst_bf,
    us16* __restrict__ Wqb, us16* __restrict__ Wkv, us16* __restrict__ Wf,
    us16* __restrict__ W2b, float* __restrict__ b1p, float* __restrict__ st,
    int n_src, int n_dst) {
  __shared__ __align__(16) us16 As[64 * 48];
  __shared__ __align__(16) us16 Bs[64 * 48];
  const int blk = blockIdx.x;
  const int t = threadIdx.x;

  if (blk < 2048) {  // ---- casts ----
    if (blk == 0) {
      float4 z = make_float4(0.f, 0.f, 0.f, 0.f);
      ((float4*)st)[t] = z;
      ((float4*)st)[t + 256] = z;
    }
    const float* srcs[7] = {src_h, dst_h, Wq, Wk, Wv, W1, W2};
    us16* dsts[7] = {src_bf, dst_bf, Wqb, Wkv, Wkv + 262144, Wf, W2b};
    int ns[7] = {n_src, n_dst, 262144, 262144, 262144, 262144, 262144};
    // 0 straight, 1 = W1a strided into 1024-wide rows, 2 = row-perm head-major
    const int md_[7] = {0, 0, 2, 2, 0, 1, 0};
    for (int rg = 0; rg < 7; ++rg) {
      const float* sp = srcs[rg];
      us16* dp = dsts[rg];
      const int mode = md_[rg];
      for (int i = (blk * 256 + t) * 4; i < ns[rg]; i += 2048 * 256 * 4) {
        int js, jd;
        if (mode == 1) {
          js = ((i >> 9) * 1024) + (i & 511);
          jd = js;
        } else if (mode == 2) {
          int r = i >> 9;
          js = i;
          jd = (PERMC(r) << 9) + (i & 511);
        } else {
          js = i; jd = i;
        }
        float4 v = *(const float4*)(sp + js);
        ushort4 o;
        o.x = f2bf(v.x); o.y = f2bf(v.y); o.z = f2bf(v.z); o.w = f2bf(v.w);
        *(ushort4*)(dp + jd) = o;
      }
    }
  } else if (blk < 2112) {  // ---- wprep: Wc[n][k] into Wf[n*1024+512+PERMC(k)]
    const int bx = (blk - 2048) & 7, byk = (blk - 2048) >> 3;
    const int w = t >> 6, lane = t & 63;
    const int lane15 = lane & 15, quad = lane >> 4;
    const int wm = w >> 1, wn = w & 1;
    const int bn_ = bx * 64, bk = byk * 64;
    floatx4 acc[2][2];
#pragma unroll
    for (int a = 0; a < 2; ++a)
#pragma unroll
      for (int c = 0; c < 2; ++c) acc[a][c] = (floatx4){0.f, 0.f, 0.f, 0.f};
    for (int j0 = 0; j0 < 512; j0 += 32) {
      {
        int n = t >> 2, jj0 = (t & 3) * 8;
        const float* rp = W1 + (size_t)(bn_ + n) * 1024 + 512 + j0 + jj0;
        float4 va = *(const float4*)(rp);
        float4 vb = *(const float4*)(rp + 4);
        ushort4 pa, pb;
        pa.x = f2bf(va.x); pa.y = f2bf(va.y); pa.z = f2bf(va.z); pa.w = f2bf(va.w);
        pb.x = f2bf(vb.x); pb.y = f2bf(vb.y); pb.z = f2bf(vb.z); pb.w = f2bf(vb.w);
        *(ushort4*)(As + n * 48 + jj0) = pa;
        *(ushort4*)(As + n * 48 + jj0 + 4) = pb;
      }
      {
        int jj = t >> 3, kc0 = (t & 7) * 8;
        const float* rp = Wm + (size_t)(j0 + jj) * 512 + bk + kc0;
        float4 va = *(const float4*)(rp);
        float4 vb = *(const float4*)(rp + 4);
        float vv[8] = {va.x, va.y, va.z, va.w, vb.x, vb.y, vb.z, vb.w};
#pragma unroll
        for (int e = 0; e < 8; ++e) Bs[(kc0 + e) * 48 + jj] = f2bf(vv[e]);
      }
      __syncthreads();
      short8 a_[2], b_[2];
#pragma unroll
      for (int mt = 0; mt < 2; ++mt)
        a_[mt] = *(const short8*)(As + (wm * 32 + mt * 16 + lane15) * 48 + quad * 8);
#pragma unroll
      for (int nt = 0; nt < 2; ++nt)
        b_[nt] = *(const short8*)(Bs + (wn * 32 + nt * 16 + lane15) * 48 + quad * 8);
#pragma unroll
      for (int mt = 0; mt < 2; ++mt)
#pragma unroll
        for (int nt = 0; nt < 2; ++nt)
          acc[mt][nt] = __builtin_amdgcn_mfma_f32_16x16x32_bf16(
              a_[mt], b_[nt], acc[mt][nt], 0, 0, 0);
      __syncthreads();
    }
#pragma unroll
    for (int mt = 0; mt < 2; ++mt) {
      int n0 = bn_ + wm * 32 + mt * 16 + quad * 4;
#pragma unroll
      for (int nt = 0; nt < 2; ++nt) {
        int k = bk + wn * 32 + nt * 16 + lane15;
        int kp = PERMC(k);
#pragma unroll
        for (int r = 0; r < 4; ++r)
          Wf[(size_t)(n0 + r) * 1024 + 512 + kp] = f2bf(acc[mt][nt][r]);
      }
    }
  } else {  // ---- b1prep: 2 blocks x 256 threads, one n per thread ----
    int n = (blk - 2112) * 256 + t;
    if (n < 512) {
      const float* rp = W1 + (size_t)n * 1024 + 512;
      float s = 0.f;
      for (int j = 0; j < 512; j += 4) {
        float4 a = *(const float4*)(rp + j);
        float4 c = *(const float4*)(bm + j);
        s += a.x * c.x + a.y * c.y + a.z * c.z + a.w * c.w;
      }
      b1p[n] = b1[n] + s;
    }
  }
}

// ---------------------------------------------------------------------------
// 64x128 MFMA GEMM body (NT), BK=64, double-buffered (48 KB -> 3 blocks/CU),
// counted vmcnt(6) (never drains to 0 in main loop), 2 raw barriers/step.
// LDS passed in (shared across phases in the fused-tail kernel).
// A row stride fixed 512; k0>=512 reads A2 (concat). M%64==0, N%128==0,
// K%64==0. W row stride = K.
// modes: 0 fp32 out + fused BN stats; 1 bf16 row-major [M][512] out with
// head-major cols (bias via IPERMC); 4 fused K/V: cols<512 row-major K
// (IPERMC bias), cols>=512 V plane layout.
// ---------------------------------------------------------------------------
__device__ inline void gemm_body(
    us16* As, us16* Bs,
    const us16* __restrict__ A1, const us16* __restrict__ A2,
    const us16* __restrict__ W,
    const float* __restrict__ bias0, const float* __restrict__ bias1,
    void* __restrict__ C0, void* __restrict__ C1, float* __restrict__ stats,
    int M, int N, int K, int mode, int bx, int by) {
  const int t = threadIdx.x, w = t >> 6, lane = t & 63;
  const int lane15 = lane & 15, quad = lane >> 4;
  const int bm = bx * 64, bn = by * 128;
  const int lrow = lane >> 3;  // 0..7
  const int sl = lane & 7;     // slot 0..7

  floatx4 acc[4][2];
#pragma unroll
  for (int a = 0; a < 4; ++a)
#pragma unroll
    for (int c = 0; c < 2; ++c) acc[a][c] = (floatx4){0.f, 0.f, 0.f, 0.f};

  const int nk = K >> 6;

#define ISSUE(i, b)                                                          \
  {                                                                          \
    int k0 = (i) << 6;                                                       \
    const us16* Ab = (k0 < 512) ? A1 : A2;                                   \
    int ka = k0 & 511;                                                       \
    _Pragma("unroll")                                                        \
    for (int p = 0; p < 2; ++p) {                                            \
      int rbase = p * 32 + w * 8;                                            \
      int row = rbase + lrow;                                                \
      int kg = sl ^ SW3(row);                                                \
      gld16(Ab + (size_t)(bm + row) * 512 + ka + kg * 8,                     \
            As + (b) * 4096 + rbase * 64);                                   \
    }                                                                        \
    _Pragma("unroll")                                                        \
    for (int p = 0; p < 4; ++p) {                                            \
      int rbase = p * 32 + w * 8;                                            \
      int row = rbase + lrow;                                                \
      int kg = sl ^ SW3(row);                                                \
      gld16(W + (size_t)(bn + row) * K + k0 + kg * 8,                        \
            Bs + (b) * 8192 + rbase * 64);                                   \
    }                                                                        \
  }

  ISSUE(0, 0);
  if (nk > 1) ISSUE(1, 1);
  for (int i = 0; i < nk; ++i) {
    const int cur = i & 1;
    if (i + 1 < nk) {
      asm volatile("s_waitcnt vmcnt(6)" ::: "memory");
    } else {
      asm volatile("s_waitcnt vmcnt(0)" ::: "memory");
    }
    __builtin_amdgcn_s_barrier();
    asm volatile("" ::: "memory");
#pragma unroll
    for (int kh = 0; kh < 2; ++kh) {
      const int g = kh * 4 + quad;
      short8 a_[4], b_[2];
#pragma unroll
      for (int mt = 0; mt < 4; ++mt) {
        int r = mt * 16 + lane15;
        a_[mt] = *(const short8*)(As + cur * 4096 + r * 64 + (g ^ SW3(r)) * 8);
      }
#pragma unroll
      for (int nt = 0; nt < 2; ++nt) {
        int c = w * 32 + nt * 16 + lane15;
        b_[nt] = *(const short8*)(Bs + cur * 8192 + c * 64 + (g ^ SW3(c)) * 8);
      }
#pragma unroll
      for (int mt = 0; mt < 4; ++mt)
#pragma unroll
        for (int nt = 0; nt < 2; ++nt)
          acc[mt][nt] = __builtin_amdgcn_mfma_f32_16x16x32_bf16(
              a_[mt], b_[nt], acc[mt][nt], 0, 0, 0);
    }
    asm volatile("" ::: "memory");
    __builtin_amdgcn_s_barrier();
    asm volatile("" ::: "memory");
    if (i + 2 < nk) ISSUE(i + 2, cur);
  }
#undef ISSUE

  if (mode == 0) {
#pragma unroll
    for (int nt = 0; nt < 2; ++nt) {
      int col = bn + w * 32 + nt * 16 + lane15;
      float bv = bias0[col];
      float s = 0.f, qq = 0.f;
#pragma unroll
      for (int mt = 0; mt < 4; ++mt) {
        int row0 = bm + mt * 16 + quad * 4;
#pragma unroll
        for (int r = 0; r < 4; ++r) {
          float val = acc[mt][nt][r] + bv;
          ((float*)C0)[(size_t)(row0 + r) * N + col] = val;
          s += val; qq = fmaf(val, val, qq);
        }
      }
      s += __shfl_xor(s, 16); s += __shfl_xor(s, 32);
      qq += __shfl_xor(qq, 16); qq += __shfl_xor(qq, 32);
      if (quad == 0) {
        atomicAdd(&stats[col], s);
        atomicAdd(&stats[512 + col], qq);
      }
    }
  } else if (mode == 1) {  // row-major [M][512] bf16, coalesced
#pragma unroll
    for (int nt = 0; nt < 2; ++nt) {
      int col = bn + w * 32 + nt * 16 + lane15;
      float bv = bias0[IPERMC(col)];
#pragma unroll
      for (int mt = 0; mt < 4; ++mt) {
        int row0 = bm + mt * 16 + quad * 4;
#pragma unroll
        for (int r = 0; r < 4; ++r)
          ((us16*)C0)[(size_t)(row0 + r) * 512 + col] = f2bf(acc[mt][nt][r] + bv);
      }
    }
  } else {  // mode 4: fused K (row-major) / V (plane layout), N=1024
#pragma unroll
    for (int nt = 0; nt < 2; ++nt) {
      int col = bn + w * 32 + nt * 16 + lane15;
      if (col < 512) {
        float bv = bias0[IPERMC(col)];
#pragma unroll
        for (int mt = 0; mt < 4; ++mt) {
          int row0 = bm + mt * 16 + quad * 4;
#pragma unroll
          for (int r = 0; r < 4; ++r)
            ((us16*)C0)[(size_t)(row0 + r) * 512 + col] = f2bf(acc[mt][nt][r] + bv);
        }
      } else {
        int cv = col - 512;
        float bv = bias1[cv];
        int plane = (cv & 7) * 64 + (cv >> 3);
#pragma unroll
        for (int mt = 0; mt < 4; ++mt) {
          int row0 = bm + mt * 16 + quad * 4;
          ushort4 pk;
          pk.x = f2bf(acc[mt][nt][0] + bv);
          pk.y = f2bf(acc[mt][nt][1] + bv);
          pk.z = f2bf(acc[mt][nt][2] + bv);
          pk.w = f2bf(acc[mt][nt][3] + bv);
          *(ushort4*)((us16*)C1 + (size_t)plane * M + row0) = pk;
        }
      }
    }
  }
}

// Q projection + fused K/V projection, one 1D dispatch, N-tile fastest,
// XCD-swizzled (grid = 1280, % 8 == 0). R2 config (verified fastest).
__global__ __launch_bounds__(256) void gemm_qkv(
    const us16* __restrict__ dst_bf, const us16* __restrict__ src_bf,
    const us16* __restrict__ Wqb, const us16* __restrict__ Wkv,
    const float* __restrict__ bq, const float* __restrict__ bk,
    const float* __restrict__ bv,
    us16* __restrict__ Qh, us16* __restrict__ Kh, us16* __restrict__ Vt,
    int Md, int Ms) {
  __shared__ __align__(16) us16 As[2 * 64 * 64];    // 16 KB
  __shared__ __align__(16) us16 Bs[2 * 128 * 64];   // 32 KB
  int b = blockIdx.x;
  int i = (b & 7) * ((int)gridDim.x >> 3) + (b >> 3);  // XCD-contiguous
  int nq = (Md / 64) * 4;
  if (i < nq) {
    gemm_body(As, Bs, dst_bf, dst_bf, Wqb, bq, nullptr, Qh, nullptr, nullptr,
              Md, 512, 512, 1, i >> 2, i & 3);
  } else {
    int j = i - nq;
    gemm_body(As, Bs, src_bf, src_bf, Wkv, bk, bv, Kh, Vt, nullptr,
              Ms, 1024, 512, 4, j >> 3, j & 7);
  }
}

// Standalone FFN GEMM (fallback path; R2-verified). Grid % 8 == 0.
__global__ __launch_bounds__(256) void gemm_ffn(
    const us16* __restrict__ A1, const us16* __restrict__ A2,
    const us16* __restrict__ W,
    const float* __restrict__ bias0, void* __restrict__ C0,
    float* __restrict__ stats, int M, int K) {
  __shared__ __align__(16) us16 As[2 * 64 * 64];
  __shared__ __align__(16) us16 Bs[2 * 128 * 64];
  int b = blockIdx.x;
  int i = (b & 7) * ((int)gridDim.x >> 3) + (b >> 3);  // XCD-contiguous
  gemm_body(As, Bs, A1, A2, W, bias0, nullptr, C0, nullptr, stats,
            M, 512, K, 0, i >> 2, i & 3);
}

// BN apply (fallback path; R2-verified).
__global__ __launch_bounds__(256) void bn_apply(
    const float* __restrict__ X, const float* __restrict__ stats,
    const float* __restrict__ g, const float* __restrict__ be,
    const float* __restrict__ resid, void* __restrict__ Y,
    int M, float invM, int relu, int out_bf) {
  const size_t total = (size_t)M * H_DIM;
  for (size_t i = (size_t)blockIdx.x * 256 + threadIdx.x; i < total;
       i += (size_t)gridDim.x * 256) {
    int c = (int)(i & (H_DIM - 1));
    float mean = stats[c] * invM;
    float var = fmaf(-mean, mean, stats[H_DIM + c] * invM);
    float x = X[i];
    float y = (x - mean) * rsqrtf(var + 1e-5f) * g[c] + be[c];
    if (relu) y = fmaxf(y, 0.f);
    if (resid) y += resid[i];
    if (out_bf) ((us16*)Y)[i] = f2bf(y);
    else ((float*)Y)[i] = y;
  }
}

// ---------------------------------------------------------------------------
// fused_tail (cooperative): FFN1 -> grid.sync -> BN1+ReLU -> grid.sync ->
// FFN2 -> grid.sync -> BN2+residual. One dispatch replaces four. Launched
// via hipLaunchCooperativeKernel so the runtime guarantees co-residency.
// Grid 376 (94 m-tiles x 4 n-tiles), 48 KB LDS.
// ---------------------------------------------------------------------------
__global__ __launch_bounds__(256) void fused_tail(
    const us16* __restrict__ dst_bf, const us16* __restrict__ Ob,
    const us16* __restrict__ Wf, const us16* __restrict__ W2b,
    const float* __restrict__ b1p, const float* __restrict__ b2,
    const float* __restrict__ g1, const float* __restrict__ be1,
    const float* __restrict__ g2, const float* __restrict__ be2,
    const float* __restrict__ dst_h,
    float* __restrict__ X1, us16* __restrict__ X1bf, float* __restrict__ X2,
    float* __restrict__ out, float* __restrict__ st, int M) {
  __shared__ __align__(16) us16 As[2 * 64 * 64];    // 16 KB
  __shared__ __align__(16) us16 Bs[2 * 128 * 64];   // 32 KB
  cg::grid_group grid = cg::this_grid();
  const int b = blockIdx.x;
  const int nblk = (int)gridDim.x;
  const int i = (b & 7) * (nblk >> 3) + (b >> 3);  // XCD-contiguous (376%8==0)
  const int bx = i >> 2, by = i & 3;
  const int t = threadIdx.x;
  const float invM = 1.f / (float)M;

  // ---- phase A: FFN1 ([dst_bf | Ob] @ Wf^T + b1p -> X1 fp32 + stats1) ----
  gemm_body(As, Bs, dst_bf, Ob, Wf, b1p, nullptr, X1, nullptr, st,
            M, 512, 1024, 0, bx, by);
  grid.sync();

  // ---- phase B: BN1 + ReLU on own (bx,by) strip -> X1bf ----
  {
    float* sl = (float*)As;
    float* tl = sl + 128;
    const int c0 = by * 128;
    if (t < 128) {
      int c = c0 + t;
      float mean = st[c] * invM;
      float var = fmaf(-mean, mean, st[512 + c] * invM);
      float inv = rsqrtf(var + 1e-5f) * g1[c];
      sl[t] = inv;
      tl[t] = be1[c] - mean * inv;
    }
    __syncthreads();
    const float* Xs = X1 + (size_t)(bx * 64) * 512 + c0;
    us16* Yd = X1bf + (size_t)(bx * 64) * 512 + c0;
    for (int j = t * 4; j < 64 * 128; j += 1024) {
      int row = j >> 7, col = j & 127;
      float4 v = *(const float4*)(Xs + (size_t)row * 512 + col);
      ushort4 o;
      o.x = f2bf(fmaxf(fmaf(v.x, sl[col], tl[col]), 0.f));
      o.y = f2bf(fmaxf(fmaf(v.y, sl[col + 1], tl[col + 1]), 0.f));
      o.z = f2bf(fmaxf(fmaf(v.z, sl[col + 2], tl[col + 2]), 0.f));
      o.w = f2bf(fmaxf(fmaf(v.w, sl[col + 3], tl[col + 3]), 0.f));
      *(ushort4*)(Yd + (size_t)row * 512 + col) = o;
    }
  }
  grid.sync();

  // ---- phase C: FFN2 (X1bf @ W2b^T + b2 -> X2 fp32 + stats2) ----
  gemm_body(As, Bs, X1bf, X1bf, W2b, b2, nullptr, X2, nullptr, st + 1024,
            M, 512, 512, 0, bx, by);
  grid.sync();

  // ---- phase D: BN2 + residual on own strip -> out (fp32) ----
  {
    float* sl = (float*)As;
    float* tl = sl + 128;
    const int c0 = by * 128;
    if (t < 128) {
      int c = c0 + t;
      float mean = st[1024 + c] * invM;
      float var = fmaf(-mean, mean, st[1536 + c] * invM);
      float inv = rsqrtf(var + 1e-5f) * g2[c];
      sl[t] = inv;
      tl[t] = be2[c] - mean * inv;
    }
    __syncthreads();
    const float* Xs = X2 + (size_t)(bx * 64) * 512 + c0;
    const float* Rs = dst_h + (size_t)(bx * 64) * 512 + c0;
    float* Yd = out + (size_t)(bx * 64) * 512 + c0;
    for (int j = t * 4; j < 64 * 128; j += 1024) {
      int row = j >> 7, col = j & 127;
      float4 v = *(const float4*)(Xs + (size_t)row * 512 + col);
      float4 rr = *(const float4*)(Rs + (size_t)row * 512 + col);
      float4 o;
      o.x = fmaf(v.x, sl[col], tl[col]) + rr.x;
      o.y = fmaf(v.y, sl[col + 1], tl[col + 1]) + rr.y;
      o.z = fmaf(v.z, sl[col + 2], tl[col + 2]) + rr.z;
      o.w = fmaf(v.w, sl[col + 3], tl[col + 3]) + rr.w;
      *(float4*)(Yd + (size_t)row * 512 + col) = o;
    }
  }
}

// ---------------------------------------------------------------------------
// attn_v6: 4 waves x 16 dst rows of one (b,h). Q/K row-major [M][512] with
// head-major cols (head h's 64 dims contiguous at col h*64). K/Vt chunks
// staged via global_load_lds (SW3 swizzle) into 2 LDS buffers with counted
// vmcnt(4); per-wave register softmax; Pw wave-private. Output Ob row-major
// [M][512] head-major -> coalesced 2B stores. Grid (16, 8, 8), 256 thr.
// ---------------------------------------------------------------------------
__global__ __launch_bounds__(256) void attn_v6(
    const us16* __restrict__ Qh, const us16* __restrict__ Kh,
    const us16* __restrict__ Vt, const int* __restrict__ dlens,
    const int* __restrict__ slens, us16* __restrict__ O,
    int Md, int Ms) {
  const int b = blockIdx.x, h = blockIdx.y, tile = blockIdx.z;
  int doff = 0, soff = 0;
  for (int i = 0; i < NBATCH; ++i)
    if (i < b) { doff += dlens[i]; soff += slens[i]; }
  const int dlen = dlens[b], slen = slens[b];
  if (tile * 64 >= dlen) return;

  __shared__ __align__(16) us16 Ks[2 * 64 * 64];   // 16 KB
  __shared__ __align__(16) us16 Vts[2 * 64 * 64];  // 16 KB
  __shared__ __align__(16) us16 Pw[4][16 * 72];

  const int t = threadIdx.x, wv = t >> 6, lane = t & 63;
  const int lane15 = lane & 15, quad = lane >> 4;
  const int i0w = tile * 64 + wv * 16;
  const bool active = i0w < dlen;  // dlen % 16 == 0

  const us16* Qp = Qh + ((size_t)(doff + (active ? i0w : 0))) * 512 + h * 64;
  const us16* Kp = Kh + ((size_t)soff) * 512 + h * 64;
  const us16* Vtp = Vt + ((size_t)h * 64) * Ms + soff;

  short8 af0 = *(const short8*)(Qp + (size_t)lane15 * 512 + quad * 8);
  short8 af1 = *(const short8*)(Qp + (size_t)lane15 * 512 + 32 + quad * 8);

  floatx4 oa[4];
#pragma unroll
  for (int nt = 0; nt < 4; ++nt) oa[nt] = (floatx4){0.f, 0.f, 0.f, 0.f};
  float m_r[4] = {-3.0e38f, -3.0e38f, -3.0e38f, -3.0e38f};
  float l_r[4] = {0.f, 0.f, 0.f, 0.f};

  const int nc = (slen + 63) >> 6;  // 64-col chunks (tail masked via `valid`)

#define KVST(c, bu)                                                       \
  {                                                                       \
    int jb = (c) << 6;                                                    \
    _Pragma("unroll")                                                     \
    for (int p = 0; p < 2; ++p) {                                         \
      int row = wv * 16 + p * 8 + (lane >> 3);                            \
      int slt = lane & 7;                                                 \
      int kg = slt ^ SW3(row);                                            \
      gld16(Kp + (size_t)(jb + row) * 512 + kg * 8,                       \
            Ks + (bu) * 4096 + (wv * 16 + p * 8) * 64);                   \
      gld16(Vtp + (size_t)row * Ms + jb + kg * 8,                         \
            Vts + (bu) * 4096 + (wv * 16 + p * 8) * 64);                  \
    }                                                                     \
  }

  KVST(0, 0);
  if (nc > 1) KVST(1, 1);
  for (int c = 0; c < nc; ++c) {
    const int cur = c & 1;
    if (c + 1 < nc) {
      asm volatile("s_waitcnt vmcnt(4)" ::: "memory");
    } else {
      asm volatile("s_waitcnt vmcnt(0)" ::: "memory");
    }
    __builtin_amdgcn_s_barrier();
    asm volatile("" ::: "memory");

    if (active) {
      const int j0 = c << 6;
      floatx4 s[4];
#pragma unroll
      for (int jt = 0; jt < 4; ++jt) {
        int j = jt * 16 + lane15;
        short8 b0 = *(const short8*)(Ks + cur * 4096 + j * 64 + ((quad ^ SW3(j)) * 8));
        short8 b1 = *(const short8*)(Ks + cur * 4096 + j * 64 + (((4 + quad) ^ SW3(j)) * 8));
        floatx4 a = (floatx4){0.f, 0.f, 0.f, 0.f};
        a = __builtin_amdgcn_mfma_f32_16x16x32_bf16(af0, b0, a, 0, 0, 0);
        a = __builtin_amdgcn_mfma_f32_16x16x32_bf16(af1, b1, a, 0, 0, 0);
        s[jt] = a;
      }
      float mx[4] = {-3.0e38f, -3.0e38f, -3.0e38f, -3.0e38f};
#pragma unroll
      for (int jt = 0; jt < 4; ++jt) {
        bool valid = (j0 + jt * 16 + lane15) < slen;
#pragma unroll
        for (int r = 0; r < 4; ++r) {
          float v = valid ? s[jt][r] * 0.125f : -3.0e38f;
          s[jt][r] = v;
          mx[r] = fmaxf(mx[r], v);
        }
      }
#pragma unroll
      for (int r = 0; r < 4; ++r) {
        mx[r] = fmaxf(mx[r], __shfl_xor(mx[r], 1));
        mx[r] = fmaxf(mx[r], __shfl_xor(mx[r], 2));
        mx[r] = fmaxf(mx[r], __shfl_xor(mx[r], 4));
        mx[r] = fmaxf(mx[r], __shfl_xor(mx[r], 8));
      }
      float al[4], sum[4];
#pragma unroll
      for (int r = 0; r < 4; ++r) {
        float mn = fmaxf(m_r[r], mx[r]);
        al[r] = __expf(m_r[r] - mn);
        m_r[r] = mn;
        sum[r] = 0.f;
      }
#pragma unroll
      for (int jt = 0; jt < 4; ++jt)
#pragma unroll
        for (int r = 0; r < 4; ++r) {
          float e = __expf(s[jt][r] - m_r[r]);
          sum[r] += e;
          Pw[wv][(quad * 4 + r) * 72 + jt * 16 + lane15] = f2bf(e);
        }
#pragma unroll
      for (int r = 0; r < 4; ++r) {
        sum[r] += __shfl_xor(sum[r], 1);
        sum[r] += __shfl_xor(sum[r], 2);
        sum[r] += __shfl_xor(sum[r], 4);
        sum[r] += __shfl_xor(sum[r], 8);
        l_r[r] = l_r[r] * al[r] + sum[r];
      }
#pragma unroll
      for (int nt = 0; nt < 4; ++nt)
#pragma unroll
        for (int r = 0; r < 4; ++r) oa[nt][r] *= al[r];
      short8 pa0 = *(const short8*)(&Pw[wv][lane15 * 72 + quad * 8]);
      short8 pa1 = *(const short8*)(&Pw[wv][lane15 * 72 + 32 + quad * 8]);
#pragma unroll
      for (int nt = 0; nt < 4; ++nt) {
        int d = nt * 16 + lane15;
        short8 v0 = *(const short8*)(Vts + cur * 4096 + d * 64 + ((quad ^ SW3(d)) * 8));
        short8 v1 = *(const short8*)(Vts + cur * 4096 + d * 64 + (((4 + quad) ^ SW3(d)) * 8));
        oa[nt] = __builtin_amdgcn_mfma_f32_16x16x32_bf16(pa0, v0, oa[nt], 0, 0, 0);
        oa[nt] = __builtin_amdgcn_mfma_f32_16x16x32_bf16(pa1, v1, oa[nt], 0, 0, 0);
      }
    }

    asm volatile("" ::: "memory");
    __builtin_amdgcn_s_barrier();  // all waves done reading buf cur
    asm volatile("" ::: "memory");
    if (c + 2 < nc) KVST(c + 2, cur);
  }
#undef KVST

  if (active) {
    float linv[4];
#pragma unroll
    for (int r = 0; r < 4; ++r) linv[r] = 1.f / l_r[r];
#pragma unroll
    for (int r = 0; r < 4; ++r) {
      int i = quad * 4 + r;
      us16* orow = O + (size_t)(doff + i0w + i) * H_DIM + h * 64;
#pragma unroll
      for (int nt = 0; nt < 4; ++nt) {
        int d = nt * 16 + lane15;
        orow[d] = f2bf(oa[nt][r] * linv[r]);
      }
    }
  }
}

// ---------------------------------------------------------------------------
extern "C" void kernel_launch(void* const* d_in, const int* in_sizes, int n_in,
                              void* d_out, int out_size, void* d_ws, size_t ws_size,
                              hipStream_t stream) {
  const float* src_h = (const float*)d_in[0];
  const float* dst_h = (const float*)d_in[1];
  const int* s_lens  = (const int*)d_in[2];
  const int* d_lens  = (const int*)d_in[3];
  const float* Wq = (const float*)d_in[4];  const float* bq = (const float*)d_in[5];
  const float* Wk = (const float*)d_in[6];  const float* bk = (const float*)d_in[7];
  const float* Wv = (const float*)d_in[8];  const float* bv = (const float*)d_in[9];
  const float* Wm = (const float*)d_in[10]; const float* bm = (const float*)d_in[11];
  const float* W1 = (const float*)d_in[12]; const float* b1 = (const float*)d_in[13];
  const float* g1 = (const float*)d_in[14]; const float* be1 = (const float*)d_in[15];
  const float* W2 = (const float*)d_in[16]; const float* b2 = (const float*)d_in[17];
  const float* g2 = (const float*)d_in[18]; const float* be2 = (const float*)d_in[19];

  const int total_src = in_sizes[0] / H_DIM;  // 7232 = 113*64
  const int total_dst = in_sizes[1] / H_DIM;  // 6016 = 94*64

  // ---- workspace layout (byte offsets); peak ~50.5 MB ----
  char* ws = (char*)d_ws;
  us16* src_bf = (us16*)(ws + 0);                    //  7,405,568
  us16* dst_bf = (us16*)(ws + 7405568);              //  6,160,384
  us16* wbf    = (us16*)(ws + 13565952);             //  3,145,728 used
  float* b1p   = (float*)(ws + 16711680);            //  2,048
  us16* Qh     = (us16*)(ws + 17235968);             //  6,160,384
  us16* Kh     = (us16*)(ws + 23396352);             //  7,405,568
  us16* Vt     = (us16*)(ws + 30801920);             //  7,405,568
  us16* Ob     = (us16*)(ws + 38207488);             //  6,160,384
  us16* X1bf   = (us16*)(ws + 44367872);             //  6,160,384
  float* st    = (float*)(ws + 50528256);            //  8,192
  float* X1    = (float*)(ws + 17235968);            // aliases Qh+Kh (dead)
  float* X2    = (float*)(ws + 30801920);            // aliases Vt+Ob (Ob dead
                                                     //  after FFN1 reads)
  float* st1 = st, *st2 = st + 1024;

  us16* Wqb = wbf;                 // 262144 elems (rows permuted head-major)
  us16* Wkv = wbf + 262144;        // 524288 (Wk rows permuted, then Wv rows)
  us16* Wf  = wbf + 786432;        // 524288 ([W1a | Wc-perm] rows of 1024)
  us16* W2b = wbf + 1310720;       // 262144

  const int mbd = total_dst / 64;  // 94
  const int mbs = total_src / 64;  // 113
  const dim3 blk256(256);

  // 1: casts + weight composites + BN-stat zero (one dispatch)
  prep_all<<<dim3(2114), blk256, 0, stream>>>(
      src_h, dst_h, Wq, Wk, Wv, W1, W2, Wm, b1, bm,
      src_bf, dst_bf, Wqb, Wkv, Wf, W2b, b1p, st,
      total_src * H_DIM, total_dst * H_DIM);

  // 2: Q + fused K/V projections (64x128 tiles, counted vmcnt, XCD-swz)
  gemm_qkv<<<dim3(mbd * 4 + mbs * 8), blk256, 0, stream>>>(
      dst_bf, src_bf, Wqb, Wkv, bq, bk, bv, Qh, Kh, Vt, total_dst, total_src);

  // 3: attention -> Ob (bf16 [M,512] head-major)
  attn_v6<<<dim3(NBATCH, N_HEADS, 8), blk256, 0, stream>>>(
      Qh, Kh, Vt, d_lens, s_lens, Ob, total_dst, total_src);

  // 4: FFN1 + BN1 + FFN2 + BN2 + residual — cooperative single dispatch,
  // with fallback to the R2-verified 4-dispatch tail if the cooperative
  // enqueue is rejected (e.g. unsupported under graph capture).
  {
    const us16* a_dst = dst_bf; const us16* a_ob = Ob;
    const us16* a_wf = Wf; const us16* a_w2 = W2b;
    const float* a_b1p = b1p; const float* a_b2 = b2;
    const float* a_g1 = g1; const float* a_be1 = be1;
    const float* a_g2 = g2; const float* a_be2 = be2;
    const float* a_dh = dst_h;
    float* a_x1 = X1; us16* a_x1bf = X1bf; float* a_x2 = X2;
    float* a_out = (float*)d_out; float* a_st = st;
    int a_m = total_dst;
    void* args[] = {&a_dst, &a_ob, &a_wf, &a_w2, &a_b1p, &a_b2,
                    &a_g1, &a_be1, &a_g2, &a_be2, &a_dh,
                    &a_x1, &a_x1bf, &a_x2, &a_out, &a_st, &a_m};
    hipError_t err = hipLaunchCooperativeKernel(
        (const void*)fused_tail, dim3(mbd * 4), blk256, args, 0, stream);
    if (err != hipSuccess) {
      // fallback: R2-verified 4-dispatch tail
      gemm_ffn<<<dim3(mbd * 4), blk256, 0, stream>>>(
          dst_bf, Ob, Wf, b1p, X1, st1, total_dst, 1024);
      bn_apply<<<dim3(512), blk256, 0, stream>>>(
          X1, st1, g1, be1, nullptr, X1bf, total_dst,
          1.f / (float)total_dst, 1, 1);
      gemm_ffn<<<dim3(mbd * 4), blk256, 0, stream>>>(
          X1bf, X1bf, W2b, b2, X2, st2, total_dst, 512);
      bn_apply<<<dim3(512), blk256, 0, stream>>>(
          X2, st2, g2, be2, dst_h, d_out, total_dst,
          1.f / (float)total_dst, 0, 0);
    }
  }
}

// Round 6
// 220.021 us; speedup vs baseline: 1.8171x; 1.8171x over previous
//
#include <hip/hip_runtime.h>
#include <hip/hip_bf16.h>

#define H_DIM 512
#define N_HEADS 8
#define HEAD_DIM 64
#define NBATCH 16

typedef __attribute__((ext_vector_type(8))) short short8;   // 8 bf16 (4 VGPRs)
typedef __attribute__((ext_vector_type(4))) float floatx4;  // MFMA acc

typedef unsigned short us16;

// 3-bit row swizzle for XOR'd LDS slots (structurally conflict-free b128)
#define SW3(r) ((((r) >> 1) & 3) | (((r) & 1) << 2))

// head-major channel permutation: c (=d*8+h) -> c' (=h*64+d)
#define PERMC(c) ((((c) & 7) << 6) | ((c) >> 3))
// inverse: c' -> c
#define IPERMC(cp) ((((cp) & 63) << 3) | ((cp) >> 6))

__device__ inline unsigned short f2bf(float f) {
  unsigned int u = __float_as_uint(f);
  unsigned int r = (u + 0x7fffu + ((u >> 16) & 1u)) >> 16;  // RNE
  return (unsigned short)r;
}

// async global->LDS, 16B/lane; lds dest = wave-uniform base + lane*16
__device__ inline void gld16(const us16* g, us16* l) {
  __builtin_amdgcn_global_load_lds(
      (const __attribute__((address_space(1))) void*)g,
      (__attribute__((address_space(3))) void*)l, 16, 0, 0);
}

// ---------------------------------------------------------------------------
// prep_all: one dispatch for (a) all fp32->bf16 casts + BN-stat zero
// [blocks 0..2047], (b) Wc = W1b @ Wm weight composite [blocks 2048..2111],
// (c) b1p = b1 + W1b @ bm [blocks 2112..2113]. All three are independent.
// Wq/Wk rows are PERMUTED to head-major (c' = PERMC(c)) so the QKV GEMM
// epilogue writes plain row-major [M][512] coalesced. Wv stays original
// (V keeps its plane layout). Wc's k-columns are permuted to match the
// head-major attention output Ob.
// ---------------------------------------------------------------------------
__global__ __launch_bounds__(256) void prep_all(
    const float* __restrict__ src_h, const float* __restrict__ dst_h,
    const float* __restrict__ Wq, const float* __restrict__ Wk,
    const float* __restrict__ Wv, const float* __restrict__ W1,
    const float* __restrict__ W2, const float* __restrict__ Wm,
    const float* __restrict__ b1, const float* __restrict__ bm,
    us16* __restrict__ src_bf, us16* __restrict__ dst_bf,
    us16* __restrict__ Wqb, us16* __restrict__ Wkv, us16* __restrict__ Wf,
    us16* __restrict__ W2b, float* __restrict__ b1p, float* __restrict__ st,
    int n_src, int n_dst) {
  __shared__ __align__(16) us16 As[64 * 48];
  __shared__ __align__(16) us16 Bs[64 * 48];
  const int blk = blockIdx.x;
  const int t = threadIdx.x;

  if (blk < 2048) {  // ---- casts ----
    if (blk == 0) {
      float4 z = make_float4(0.f, 0.f, 0.f, 0.f);
      ((float4*)st)[t] = z;
      ((float4*)st)[t + 256] = z;
    }
    const float* srcs[7] = {src_h, dst_h, Wq, Wk, Wv, W1, W2};
    us16* dsts[7] = {src_bf, dst_bf, Wqb, Wkv, Wkv + 262144, Wf, W2b};
    int ns[7] = {n_src, n_dst, 262144, 262144, 262144, 262144, 262144};
    // 0 straight, 1 = W1a strided into 1024-wide rows, 2 = row-perm head-major
    const int md_[7] = {0, 0, 2, 2, 0, 1, 0};
    for (int rg = 0; rg < 7; ++rg) {
      const float* sp = srcs[rg];
      us16* dp = dsts[rg];
      const int mode = md_[rg];
      for (int i = (blk * 256 + t) * 4; i < ns[rg]; i += 2048 * 256 * 4) {
        int js, jd;
        if (mode == 1) {
          js = ((i >> 9) * 1024) + (i & 511);
          jd = js;
        } else if (mode == 2) {
          int r = i >> 9;
          js = i;
          jd = (PERMC(r) << 9) + (i & 511);
        } else {
          js = i; jd = i;
        }
        float4 v = *(const float4*)(sp + js);
        ushort4 o;
        o.x = f2bf(v.x); o.y = f2bf(v.y); o.z = f2bf(v.z); o.w = f2bf(v.w);
        *(ushort4*)(dp + jd) = o;
      }
    }
  } else if (blk < 2112) {  // ---- wprep: Wc[n][k] into Wf[n*1024+512+PERMC(k)]
    const int bx = (blk - 2048) & 7, byk = (blk - 2048) >> 3;
    const int w = t >> 6, lane = t & 63;
    const int lane15 = lane & 15, quad = lane >> 4;
    const int wm = w >> 1, wn = w & 1;
    const int bn_ = bx * 64, bk = byk * 64;
    floatx4 acc[2][2];
#pragma unroll
    for (int a = 0; a < 2; ++a)
#pragma unroll
      for (int c = 0; c < 2; ++c) acc[a][c] = (floatx4){0.f, 0.f, 0.f, 0.f};
    for (int j0 = 0; j0 < 512; j0 += 32) {
      {
        int n = t >> 2, jj0 = (t & 3) * 8;
        const float* rp = W1 + (size_t)(bn_ + n) * 1024 + 512 + j0 + jj0;
        float4 va = *(const float4*)(rp);
        float4 vb = *(const float4*)(rp + 4);
        ushort4 pa, pb;
        pa.x = f2bf(va.x); pa.y = f2bf(va.y); pa.z = f2bf(va.z); pa.w = f2bf(va.w);
        pb.x = f2bf(vb.x); pb.y = f2bf(vb.y); pb.z = f2bf(vb.z); pb.w = f2bf(vb.w);
        *(ushort4*)(As + n * 48 + jj0) = pa;
        *(ushort4*)(As + n * 48 + jj0 + 4) = pb;
      }
      {
        int jj = t >> 3, kc0 = (t & 7) * 8;
        const float* rp = Wm + (size_t)(j0 + jj) * 512 + bk + kc0;
        float4 va = *(const float4*)(rp);
        float4 vb = *(const float4*)(rp + 4);
        float vv[8] = {va.x, va.y, va.z, va.w, vb.x, vb.y, vb.z, vb.w};
#pragma unroll
        for (int e = 0; e < 8; ++e) Bs[(kc0 + e) * 48 + jj] = f2bf(vv[e]);
      }
      __syncthreads();
      short8 a_[2], b_[2];
#pragma unroll
      for (int mt = 0; mt < 2; ++mt)
        a_[mt] = *(const short8*)(As + (wm * 32 + mt * 16 + lane15) * 48 + quad * 8);
#pragma unroll
      for (int nt = 0; nt < 2; ++nt)
        b_[nt] = *(const short8*)(Bs + (wn * 32 + nt * 16 + lane15) * 48 + quad * 8);
#pragma unroll
      for (int mt = 0; mt < 2; ++mt)
#pragma unroll
        for (int nt = 0; nt < 2; ++nt)
          acc[mt][nt] = __builtin_amdgcn_mfma_f32_16x16x32_bf16(
              a_[mt], b_[nt], acc[mt][nt], 0, 0, 0);
      __syncthreads();
    }
#pragma unroll
    for (int mt = 0; mt < 2; ++mt) {
      int n0 = bn_ + wm * 32 + mt * 16 + quad * 4;
#pragma unroll
      for (int nt = 0; nt < 2; ++nt) {
        int k = bk + wn * 32 + nt * 16 + lane15;
        int kp = PERMC(k);
#pragma unroll
        for (int r = 0; r < 4; ++r)
          Wf[(size_t)(n0 + r) * 1024 + 512 + kp] = f2bf(acc[mt][nt][r]);
      }
    }
  } else {  // ---- b1prep: 2 blocks x 256 threads, one n per thread ----
    int n = (blk - 2112) * 256 + t;
    if (n < 512) {
      const float* rp = W1 + (size_t)n * 1024 + 512;
      float s = 0.f;
      for (int j = 0; j < 512; j += 4) {
        float4 a = *(const float4*)(rp + j);
        float4 c = *(const float4*)(bm + j);
        s += a.x * c.x + a.y * c.y + a.z * c.z + a.w * c.w;
      }
      b1p[n] = b1[n] + s;
    }
  }
}

// ---------------------------------------------------------------------------
// 64x128 MFMA GEMM body (NT), BK=64, double-buffered (48 KB -> 3 blocks/CU)
// with COUNTED vmcnt: per K-step {wait vmcnt(6); barrier; compute; barrier;
// issue chunk i+2 into the buffer just freed}. Loads stay in flight across
// a full compute phase; vmcnt never drains to 0 in the main loop.
// A row stride fixed 512; k0>=512 reads A2 (concat). M%64==0, N%128==0,
// K%64==0. W row stride = K.
// modes: 0 fp32 out + fused BN stats; 1 bf16 row-major [M][512] out with
// head-major cols (bias via IPERMC); 4 fused K/V: cols<512 row-major K
// (IPERMC bias), cols>=512 V plane layout.
// ---------------------------------------------------------------------------
__device__ inline void gemm_body(
    const us16* __restrict__ A1, const us16* __restrict__ A2,
    const us16* __restrict__ W,
    const float* __restrict__ bias0, const float* __restrict__ bias1,
    void* __restrict__ C0, void* __restrict__ C1, float* __restrict__ stats,
    int M, int N, int K, int mode, int bx, int by) {
  __shared__ __align__(16) us16 As[2 * 64 * 64];    // 16 KB
  __shared__ __align__(16) us16 Bs[2 * 128 * 64];   // 32 KB
  const int t = threadIdx.x, w = t >> 6, lane = t & 63;
  const int lane15 = lane & 15, quad = lane >> 4;
  const int bm = bx * 64, bn = by * 128;
  const int lrow = lane >> 3;  // 0..7
  const int sl = lane & 7;     // slot 0..7

  floatx4 acc[4][2];
#pragma unroll
  for (int a = 0; a < 4; ++a)
#pragma unroll
    for (int c = 0; c < 2; ++c) acc[a][c] = (floatx4){0.f, 0.f, 0.f, 0.f};

  const int nk = K >> 6;

#define ISSUE(i, b)                                                          \
  {                                                                          \
    int k0 = (i) << 6;                                                       \
    const us16* Ab = (k0 < 512) ? A1 : A2;                                   \
    int ka = k0 & 511;                                                       \
    _Pragma("unroll")                                                        \
    for (int p = 0; p < 2; ++p) {                                            \
      int rbase = p * 32 + w * 8;                                            \
      int row = rbase + lrow;                                                \
      int kg = sl ^ SW3(row);                                                \
      gld16(Ab + (size_t)(bm + row) * 512 + ka + kg * 8,                     \
            As + (b) * 4096 + rbase * 64);                                   \
    }                                                                        \
    _Pragma("unroll")                                                        \
    for (int p = 0; p < 4; ++p) {                                            \
      int rbase = p * 32 + w * 8;                                            \
      int row = rbase + lrow;                                                \
      int kg = sl ^ SW3(row);                                                \
      gld16(W + (size_t)(bn + row) * K + k0 + kg * 8,                        \
            Bs + (b) * 8192 + rbase * 64);                                   \
    }                                                                        \
  }

  ISSUE(0, 0);
  if (nk > 1) ISSUE(1, 1);
  for (int i = 0; i < nk; ++i) {
    const int cur = i & 1;
    if (i + 1 < nk) {
      asm volatile("s_waitcnt vmcnt(6)" ::: "memory");
    } else {
      asm volatile("s_waitcnt vmcnt(0)" ::: "memory");
    }
    __builtin_amdgcn_s_barrier();
    asm volatile("" ::: "memory");
#pragma unroll
    for (int kh = 0; kh < 2; ++kh) {
      const int g = kh * 4 + quad;
      short8 a_[4], b_[2];
#pragma unroll
      for (int mt = 0; mt < 4; ++mt) {
        int r = mt * 16 + lane15;
        a_[mt] = *(const short8*)(As + cur * 4096 + r * 64 + (g ^ SW3(r)) * 8);
      }
#pragma unroll
      for (int nt = 0; nt < 2; ++nt) {
        int c = w * 32 + nt * 16 + lane15;
        b_[nt] = *(const short8*)(Bs + cur * 8192 + c * 64 + (g ^ SW3(c)) * 8);
      }
#pragma unroll
      for (int mt = 0; mt < 4; ++mt)
#pragma unroll
        for (int nt = 0; nt < 2; ++nt)
          acc[mt][nt] = __builtin_amdgcn_mfma_f32_16x16x32_bf16(
              a_[mt], b_[nt], acc[mt][nt], 0, 0, 0);
    }
    asm volatile("" ::: "memory");
    __builtin_amdgcn_s_barrier();
    asm volatile("" ::: "memory");
    if (i + 2 < nk) ISSUE(i + 2, cur);
  }
#undef ISSUE

  if (mode == 0) {
#pragma unroll
    for (int nt = 0; nt < 2; ++nt) {
      int col = bn + w * 32 + nt * 16 + lane15;
      float bv = bias0[col];
      float s = 0.f, qq = 0.f;
#pragma unroll
      for (int mt = 0; mt < 4; ++mt) {
        int row0 = bm + mt * 16 + quad * 4;
#pragma unroll
        for (int r = 0; r < 4; ++r) {
          float val = acc[mt][nt][r] + bv;
          ((float*)C0)[(size_t)(row0 + r) * N + col] = val;
          s += val; qq = fmaf(val, val, qq);
        }
      }
      s += __shfl_xor(s, 16); s += __shfl_xor(s, 32);
      qq += __shfl_xor(qq, 16); qq += __shfl_xor(qq, 32);
      if (quad == 0) {
        atomicAdd(&stats[col], s);
        atomicAdd(&stats[512 + col], qq);
      }
    }
  } else if (mode == 1) {  // row-major [M][512] bf16, coalesced
#pragma unroll
    for (int nt = 0; nt < 2; ++nt) {
      int col = bn + w * 32 + nt * 16 + lane15;
      float bv = bias0[IPERMC(col)];
#pragma unroll
      for (int mt = 0; mt < 4; ++mt) {
        int row0 = bm + mt * 16 + quad * 4;
#pragma unroll
        for (int r = 0; r < 4; ++r)
          ((us16*)C0)[(size_t)(row0 + r) * 512 + col] = f2bf(acc[mt][nt][r] + bv);
      }
    }
  } else {  // mode 4: fused K (row-major) / V (plane layout), N=1024
#pragma unroll
    for (int nt = 0; nt < 2; ++nt) {
      int col = bn + w * 32 + nt * 16 + lane15;
      if (col < 512) {
        float bv = bias0[IPERMC(col)];
#pragma unroll
        for (int mt = 0; mt < 4; ++mt) {
          int row0 = bm + mt * 16 + quad * 4;
#pragma unroll
          for (int r = 0; r < 4; ++r)
            ((us16*)C0)[(size_t)(row0 + r) * 512 + col] = f2bf(acc[mt][nt][r] + bv);
        }
      } else {
        int cv = col - 512;
        float bv = bias1[cv];
        int plane = (cv & 7) * 64 + (cv >> 3);
#pragma unroll
        for (int mt = 0; mt < 4; ++mt) {
          int row0 = bm + mt * 16 + quad * 4;
          ushort4 pk;
          pk.x = f2bf(acc[mt][nt][0] + bv);
          pk.y = f2bf(acc[mt][nt][1] + bv);
          pk.z = f2bf(acc[mt][nt][2] + bv);
          pk.w = f2bf(acc[mt][nt][3] + bv);
          *(ushort4*)((us16*)C1 + (size_t)plane * M + row0) = pk;
        }
      }
    }
  }
}

// FFN1 GEMM: 1D grid, N-tile fastest (4 n-tiles) for A-panel reuse.
// XCD swizzle (grid % 8 == 0).
__global__ __launch_bounds__(256) void gemm_ffn(
    const us16* __restrict__ A1, const us16* __restrict__ A2,
    const us16* __restrict__ W,
    const float* __restrict__ bias0, void* __restrict__ C0,
    float* __restrict__ stats, int M, int K) {
  int b = blockIdx.x;
  int i = (b & 7) * ((int)gridDim.x >> 3) + (b >> 3);  // XCD-contiguous
  gemm_body(A1, A2, W, bias0, nullptr, C0, nullptr, stats, M, 512, K, 0,
            i >> 2, i & 3);
}

// Q projection + fused K/V projection, one 1D dispatch, N-tile fastest,
// XCD-swizzled (grid = 1280, % 8 == 0). R2 config (verified fastest).
__global__ __launch_bounds__(256) void gemm_qkv(
    const us16* __restrict__ dst_bf, const us16* __restrict__ src_bf,
    const us16* __restrict__ Wqb, const us16* __restrict__ Wkv,
    const float* __restrict__ bq, const float* __restrict__ bk,
    const float* __restrict__ bv,
    us16* __restrict__ Qh, us16* __restrict__ Kh, us16* __restrict__ Vt,
    int Md, int Ms) {
  int b = blockIdx.x;
  int i = (b & 7) * ((int)gridDim.x >> 3) + (b >> 3);  // XCD-contiguous
  int nq = (Md / 64) * 4;
  if (i < nq) {
    gemm_body(dst_bf, dst_bf, Wqb, bq, nullptr, Qh, nullptr, nullptr,
              Md, 512, 512, 1, i >> 2, i & 3);
  } else {
    int j = i - nq;
    gemm_body(src_bf, src_bf, Wkv, bk, bv, Kh, Vt, nullptr,
              Ms, 1024, 512, 4, j >> 3, j & 7);
  }
}

// ---------------------------------------------------------------------------
// gemm_ffn2bn: FFN2 with BN1+ReLU fused into A-staging.
// C = BN1ReLU(X1) @ W2b^T + b2 -> X2 fp32 + BN2 stats. K = 512 (nk = 8).
// A-side: reg-staged (4x float4 fp32 per thread per chunk), BN applied via
// per-column tables (built once from st1), RNE-cast to bf16, ds_write into
// the same swizzled As layout. Bit-identical to bn_apply -> X1bf -> gemm.
// B-side: verified gld16 path. Counted wait = vmcnt(8) ({A_i,B_i} complete,
// {A_i+1,B_i+1} in flight); issue groups pinned with asm memory clobbers.
// LDS 52 KB -> 3 blocks/CU. Removes the bn_apply(BN1) dispatch + 12.4 MB
// of X1bf round-trip traffic.
// ---------------------------------------------------------------------------
__global__ __launch_bounds__(256) void gemm_ffn2bn(
    const float* __restrict__ X1, const us16* __restrict__ W,
    const float* __restrict__ st1, const float* __restrict__ g1,
    const float* __restrict__ be1, const float* __restrict__ b2,
    float* __restrict__ X2, float* __restrict__ st2, int M, float invM) {
  __shared__ __align__(16) us16 As[2 * 64 * 64];    // 16 KB
  __shared__ __align__(16) us16 Bs[2 * 128 * 64];   // 32 KB
  __shared__ float slt[512], tlt[512];              //  4 KB
  int b = blockIdx.x;
  int i0 = (b & 7) * ((int)gridDim.x >> 3) + (b >> 3);  // XCD-contiguous
  const int bx = i0 >> 2, by = i0 & 3;
  const int t = threadIdx.x, w = t >> 6, lane = t & 63;
  const int lane15 = lane & 15, quad = lane >> 4;
  const int bm = bx * 64, bn = by * 128;
  const int lrow = lane >> 3;  // 0..7
  const int sl = lane & 7;     // slot 0..7

  // BN1 per-column scale/shift tables (identical math to bn_apply)
  for (int c = t; c < 512; c += 256) {
    float mean = st1[c] * invM;
    float var = fmaf(-mean, mean, st1[512 + c] * invM);
    float inv = rsqrtf(var + 1e-5f) * g1[c];
    slt[c] = inv;
    tlt[c] = be1[c] - mean * inv;
  }
  __syncthreads();

  floatx4 acc[4][2];
#pragma unroll
  for (int a = 0; a < 4; ++a)
#pragma unroll
    for (int c = 0; c < 2; ++c) acc[a][c] = (floatx4){0.f, 0.f, 0.f, 0.f};

  const int arow = t >> 2;        // 0..63
  const int ac4 = (t & 3) * 16;   // col offset within 64-wide chunk
  const int s0 = (t & 3) * 2;     // first of 2 slots this thread writes

#define ALOAD(dst, ii)                                                       \
  {                                                                          \
    const float* p_ = X1 + (size_t)(bm + arow) * 512 + ((ii) << 6) + ac4;    \
    dst[0] = *(const float4*)(p_);                                           \
    dst[1] = *(const float4*)(p_ + 4);                                       \
    dst[2] = *(const float4*)(p_ + 8);                                       \
    dst[3] = *(const float4*)(p_ + 12);                                      \
  }

#define BISSUE(ii, bb)                                                       \
  {                                                                          \
    int k0 = (ii) << 6;                                                      \
    _Pragma("unroll")                                                        \
    for (int p = 0; p < 4; ++p) {                                            \
      int rbase = p * 32 + w * 8;                                            \
      int row = rbase + lrow;                                                \
      int kg = sl ^ SW3(row);                                                \
      gld16(W + (size_t)(bn + row) * 512 + k0 + kg * 8,                      \
            Bs + (bb) * 8192 + rbase * 64);                                  \
    }                                                                        \
  }

  float4 areg[2][4];
  // pinned issue order: group0 {A0,B0}, then group1 {A1,B1}
  ALOAD(areg[0], 0);
  BISSUE(0, 0);
  asm volatile("" ::: "memory");
  ALOAD(areg[1], 1);
  BISSUE(1, 1);

#pragma unroll
  for (int i = 0; i < 8; ++i) {
    const int cur = i & 1;
    if (i + 1 < 8) {
      asm volatile("s_waitcnt vmcnt(8)" ::: "memory");  // {A_i,B_i} done
    } else {
      asm volatile("s_waitcnt vmcnt(0)" ::: "memory");
    }
    // BN1+ReLU+cvt A chunk i -> As[cur]
    {
      const int k0 = i << 6;
      __align__(16) us16 vv[16];
#pragma unroll
      for (int q = 0; q < 4; ++q) {
#pragma unroll
        for (int j = 0; j < 4; ++j) {
          int c = k0 + ac4 + q * 4 + j;
          float x = ((const float*)&areg[cur][q])[j];
          float y = fmaxf(fmaf(x, slt[c], tlt[c]), 0.f);
          vv[q * 4 + j] = f2bf(y);
        }
      }
      us16* base = As + cur * 4096 + arow * 64;
      *(short8*)(base + ((s0 ^ SW3(arow)) * 8)) = *(short8*)&vv[0];
      *(short8*)(base + (((s0 + 1) ^ SW3(arow)) * 8)) = *(short8*)&vv[8];
    }
    asm volatile("s_waitcnt lgkmcnt(0)" ::: "memory");
    __builtin_amdgcn_s_barrier();
    asm volatile("" ::: "memory");
    // compute chunk i
#pragma unroll
    for (int kh = 0; kh < 2; ++kh) {
      const int g = kh * 4 + quad;
      short8 a_[4], b_[2];
#pragma unroll
      for (int mt = 0; mt < 4; ++mt) {
        int r = mt * 16 + lane15;
        a_[mt] = *(const short8*)(As + cur * 4096 + r * 64 + (g ^ SW3(r)) * 8);
      }
#pragma unroll
      for (int nt = 0; nt < 2; ++nt) {
        int c = w * 32 + nt * 16 + lane15;
        b_[nt] = *(const short8*)(Bs + cur * 8192 + c * 64 + (g ^ SW3(c)) * 8);
      }
#pragma unroll
      for (int mt = 0; mt < 4; ++mt)
#pragma unroll
        for (int nt = 0; nt < 2; ++nt)
          acc[mt][nt] = __builtin_amdgcn_mfma_f32_16x16x32_bf16(
              a_[mt], b_[nt], acc[mt][nt], 0, 0, 0);
    }
    asm volatile("" ::: "memory");
    __builtin_amdgcn_s_barrier();
    asm volatile("" ::: "memory");
    if (i + 2 < 8) {
      ALOAD(areg[cur], i + 2);
      BISSUE(i + 2, cur);
    }
  }
#undef ALOAD
#undef BISSUE

  // epilogue: fp32 out + BN2 stats (mode-0 equivalent)
#pragma unroll
  for (int nt = 0; nt < 2; ++nt) {
    int col = bn + w * 32 + nt * 16 + lane15;
    float bv = b2[col];
    float s = 0.f, qq = 0.f;
#pragma unroll
    for (int mt = 0; mt < 4; ++mt) {
      int row0 = bm + mt * 16 + quad * 4;
#pragma unroll
      for (int r = 0; r < 4; ++r) {
        float val = acc[mt][nt][r] + bv;
        X2[(size_t)(row0 + r) * 512 + col] = val;
        s += val; qq = fmaf(val, val, qq);
      }
    }
    s += __shfl_xor(s, 16); s += __shfl_xor(s, 32);
    qq += __shfl_xor(qq, 16); qq += __shfl_xor(qq, 32);
    if (quad == 0) {
      atomicAdd(&st2[col], s);
      atomicAdd(&st2[512 + col], qq);
    }
  }
}

// ---------------------------------------------------------------------------
// attn_v6: 4 waves x 16 dst rows of one (b,h). Q/K row-major [M][512] with
// head-major cols (head h's 64 dims contiguous at col h*64). K/Vt chunks
// staged via global_load_lds (SW3 swizzle) into 2 LDS buffers with counted
// vmcnt(4); per-wave register softmax; Pw wave-private. Output Ob row-major
// [M][512] head-major -> coalesced 2B stores. Grid (16, 8, 8), 256 thr.
// ---------------------------------------------------------------------------
__global__ __launch_bounds__(256) void attn_v6(
    const us16* __restrict__ Qh, const us16* __restrict__ Kh,
    const us16* __restrict__ Vt, const int* __restrict__ dlens,
    const int* __restrict__ slens, us16* __restrict__ O,
    int Md, int Ms) {
  const int b = blockIdx.x, h = blockIdx.y, tile = blockIdx.z;
  int doff = 0, soff = 0;
  for (int i = 0; i < NBATCH; ++i)
    if (i < b) { doff += dlens[i]; soff += slens[i]; }
  const int dlen = dlens[b], slen = slens[b];
  if (tile * 64 >= dlen) return;

  __shared__ __align__(16) us16 Ks[2 * 64 * 64];   // 16 KB
  __shared__ __align__(16) us16 Vts[2 * 64 * 64];  // 16 KB
  __shared__ __align__(16) us16 Pw[4][16 * 72];

  const int t = threadIdx.x, wv = t >> 6, lane = t & 63;
  const int lane15 = lane & 15, quad = lane >> 4;
  const int i0w = tile * 64 + wv * 16;
  const bool active = i0w < dlen;  // dlen % 16 == 0

  const us16* Qp = Qh + ((size_t)(doff + (active ? i0w : 0))) * 512 + h * 64;
  const us16* Kp = Kh + ((size_t)soff) * 512 + h * 64;
  const us16* Vtp = Vt + ((size_t)h * 64) * Ms + soff;

  short8 af0 = *(const short8*)(Qp + (size_t)lane15 * 512 + quad * 8);
  short8 af1 = *(const short8*)(Qp + (size_t)lane15 * 512 + 32 + quad * 8);

  floatx4 oa[4];
#pragma unroll
  for (int nt = 0; nt < 4; ++nt) oa[nt] = (floatx4){0.f, 0.f, 0.f, 0.f};
  float m_r[4] = {-3.0e38f, -3.0e38f, -3.0e38f, -3.0e38f};
  float l_r[4] = {0.f, 0.f, 0.f, 0.f};

  const int nc = (slen + 63) >> 6;  // 64-col chunks (tail masked via `valid`)

#define KVST(c, bu)                                                       \
  {                                                                       \
    int jb = (c) << 6;                                                    \
    _Pragma("unroll")                                                     \
    for (int p = 0; p < 2; ++p) {                                         \
      int row = wv * 16 + p * 8 + (lane >> 3);                            \
      int slt = lane & 7;                                                 \
      int kg = slt ^ SW3(row);                                            \
      gld16(Kp + (size_t)(jb + row) * 512 + kg * 8,                       \
            Ks + (bu) * 4096 + (wv * 16 + p * 8) * 64);                   \
      gld16(Vtp + (size_t)row * Ms + jb + kg * 8,                         \
            Vts + (bu) * 4096 + (wv * 16 + p * 8) * 64);                  \
    }                                                                     \
  }

  KVST(0, 0);
  if (nc > 1) KVST(1, 1);
  for (int c = 0; c < nc; ++c) {
    const int cur = c & 1;
    if (c + 1 < nc) {
      asm volatile("s_waitcnt vmcnt(4)" ::: "memory");
    } else {
      asm volatile("s_waitcnt vmcnt(0)" ::: "memory");
    }
    __builtin_amdgcn_s_barrier();
    asm volatile("" ::: "memory");

    if (active) {
      const int j0 = c << 6;
      floatx4 s[4];
#pragma unroll
      for (int jt = 0; jt < 4; ++jt) {
        int j = jt * 16 + lane15;
        short8 b0 = *(const short8*)(Ks + cur * 4096 + j * 64 + ((quad ^ SW3(j)) * 8));
        short8 b1 = *(const short8*)(Ks + cur * 4096 + j * 64 + (((4 + quad) ^ SW3(j)) * 8));
        floatx4 a = (floatx4){0.f, 0.f, 0.f, 0.f};
        a = __builtin_amdgcn_mfma_f32_16x16x32_bf16(af0, b0, a, 0, 0, 0);
        a = __builtin_amdgcn_mfma_f32_16x16x32_bf16(af1, b1, a, 0, 0, 0);
        s[jt] = a;
      }
      float mx[4] = {-3.0e38f, -3.0e38f, -3.0e38f, -3.0e38f};
#pragma unroll
      for (int jt = 0; jt < 4; ++jt) {
        bool valid = (j0 + jt * 16 + lane15) < slen;
#pragma unroll
        for (int r = 0; r < 4; ++r) {
          float v = valid ? s[jt][r] * 0.125f : -3.0e38f;
          s[jt][r] = v;
          mx[r] = fmaxf(mx[r], v);
        }
      }
#pragma unroll
      for (int r = 0; r < 4; ++r) {
        mx[r] = fmaxf(mx[r], __shfl_xor(mx[r], 1));
        mx[r] = fmaxf(mx[r], __shfl_xor(mx[r], 2));
        mx[r] = fmaxf(mx[r], __shfl_xor(mx[r], 4));
        mx[r] = fmaxf(mx[r], __shfl_xor(mx[r], 8));
      }
      float al[4], sum[4];
#pragma unroll
      for (int r = 0; r < 4; ++r) {
        float mn = fmaxf(m_r[r], mx[r]);
        al[r] = __expf(m_r[r] - mn);
        m_r[r] = mn;
        sum[r] = 0.f;
      }
#pragma unroll
      for (int jt = 0; jt < 4; ++jt)
#pragma unroll
        for (int r = 0; r < 4; ++r) {
          float e = __expf(s[jt][r] - m_r[r]);
          sum[r] += e;
          Pw[wv][(quad * 4 + r) * 72 + jt * 16 + lane15] = f2bf(e);
        }
#pragma unroll
      for (int r = 0; r < 4; ++r) {
        sum[r] += __shfl_xor(sum[r], 1);
        sum[r] += __shfl_xor(sum[r], 2);
        sum[r] += __shfl_xor(sum[r], 4);
        sum[r] += __shfl_xor(sum[r], 8);
        l_r[r] = l_r[r] * al[r] + sum[r];
      }
#pragma unroll
      for (int nt = 0; nt < 4; ++nt)
#pragma unroll
        for (int r = 0; r < 4; ++r) oa[nt][r] *= al[r];
      short8 pa0 = *(const short8*)(&Pw[wv][lane15 * 72 + quad * 8]);
      short8 pa1 = *(const short8*)(&Pw[wv][lane15 * 72 + 32 + quad * 8]);
#pragma unroll
      for (int nt = 0; nt < 4; ++nt) {
        int d = nt * 16 + lane15;
        short8 v0 = *(const short8*)(Vts + cur * 4096 + d * 64 + ((quad ^ SW3(d)) * 8));
        short8 v1 = *(const short8*)(Vts + cur * 4096 + d * 64 + (((4 + quad) ^ SW3(d)) * 8));
        oa[nt] = __builtin_amdgcn_mfma_f32_16x16x32_bf16(pa0, v0, oa[nt], 0, 0, 0);
        oa[nt] = __builtin_amdgcn_mfma_f32_16x16x32_bf16(pa1, v1, oa[nt], 0, 0, 0);
      }
    }

    asm volatile("" ::: "memory");
    __builtin_amdgcn_s_barrier();  // all waves done reading buf cur
    asm volatile("" ::: "memory");
    if (c + 2 < nc) KVST(c + 2, cur);
  }
#undef KVST

  if (active) {
    float linv[4];
#pragma unroll
    for (int r = 0; r < 4; ++r) linv[r] = 1.f / l_r[r];
#pragma unroll
    for (int r = 0; r < 4; ++r) {
      int i = quad * 4 + r;
      us16* orow = O + (size_t)(doff + i0w + i) * H_DIM + h * 64;
#pragma unroll
      for (int nt = 0; nt < 4; ++nt) {
        int d = nt * 16 + lane15;
        orow[d] = f2bf(oa[nt][r] * linv[r]);
      }
    }
  }
}

// ---------------------------------------------------------------------------
// bn2_apply: BN2 + residual -> fp32 out, float4-vectorized (G13).
// ---------------------------------------------------------------------------
__global__ __launch_bounds__(256) void bn2_apply(
    const float* __restrict__ X, const float* __restrict__ stats,
    const float* __restrict__ g, const float* __restrict__ be,
    const float* __restrict__ resid, float* __restrict__ Y,
    int M, float invM) {
  const size_t total4 = (size_t)M * (H_DIM / 4);
  for (size_t i = (size_t)blockIdx.x * 256 + threadIdx.x; i < total4;
       i += (size_t)gridDim.x * 256) {
    int c = (int)((i * 4) & (H_DIM - 1));
    float4 x = ((const float4*)X)[i];
    float4 rr = ((const float4*)resid)[i];
    float4 o;
#pragma unroll
    for (int j = 0; j < 4; ++j) {
      int cc = c + j;
      float mean = stats[cc] * invM;
      float var = fmaf(-mean, mean, stats[H_DIM + cc] * invM);
      float inv = rsqrtf(var + 1e-5f) * g[cc];
      float xv = ((const float*)&x)[j];
      ((float*)&o)[j] = (xv - mean) * inv + be[cc] + ((const float*)&rr)[j];
    }
    ((float4*)Y)[i] = o;
  }
}

// ---------------------------------------------------------------------------
extern "C" void kernel_launch(void* const* d_in, const int* in_sizes, int n_in,
                              void* d_out, int out_size, void* d_ws, size_t ws_size,
                              hipStream_t stream) {
  const float* src_h = (const float*)d_in[0];
  const float* dst_h = (const float*)d_in[1];
  const int* s_lens  = (const int*)d_in[2];
  const int* d_lens  = (const int*)d_in[3];
  const float* Wq = (const float*)d_in[4];  const float* bq = (const float*)d_in[5];
  const float* Wk = (const float*)d_in[6];  const float* bk = (const float*)d_in[7];
  const float* Wv = (const float*)d_in[8];  const float* bv = (const float*)d_in[9];
  const float* Wm = (const float*)d_in[10]; const float* bm = (const float*)d_in[11];
  const float* W1 = (const float*)d_in[12]; const float* b1 = (const float*)d_in[13];
  const float* g1 = (const float*)d_in[14]; const float* be1 = (const float*)d_in[15];
  const float* W2 = (const float*)d_in[16]; const float* b2 = (const float*)d_in[17];
  const float* g2 = (const float*)d_in[18]; const float* be2 = (const float*)d_in[19];

  const int total_src = in_sizes[0] / H_DIM;  // 7232 = 113*64
  const int total_dst = in_sizes[1] / H_DIM;  // 6016 = 94*64

  // ---- workspace layout (byte offsets); peak ~50.5 MB ----
  char* ws = (char*)d_ws;
  us16* src_bf = (us16*)(ws + 0);                    //  7,405,568
  us16* dst_bf = (us16*)(ws + 7405568);              //  6,160,384
  us16* wbf    = (us16*)(ws + 13565952);             //  3,145,728 used
  float* b1p   = (float*)(ws + 16711680);            //  2,048
  us16* Qh     = (us16*)(ws + 17235968);             //  6,160,384
  us16* Kh     = (us16*)(ws + 23396352);             //  7,405,568
  us16* Vt     = (us16*)(ws + 30801920);             //  7,405,568
  us16* Ob     = (us16*)(ws + 38207488);             //  6,160,384
  float* st    = (float*)(ws + 50528256);            //  8,192
  float* X1    = (float*)(ws + 17235968);            // aliases Qh+Kh (dead)
  float* X2    = (float*)(ws + 30801920);            // aliases Vt (dead after
                                                     //  attn; Ob read by FFN1
                                                     //  completes first)
  float* st1 = st, *st2 = st + 1024;

  us16* Wqb = wbf;                 // 262144 elems (rows permuted head-major)
  us16* Wkv = wbf + 262144;        // 524288 (Wk rows permuted, then Wv rows)
  us16* Wf  = wbf + 786432;        // 524288 ([W1a | Wc-perm] rows of 1024)
  us16* W2b = wbf + 1310720;       // 262144

  const int mbd = total_dst / 64;  // 94
  const int mbs = total_src / 64;  // 113
  const dim3 blk256(256);
  const float invM = 1.f / (float)total_dst;

  // 1: casts + weight composites + BN-stat zero (one dispatch)
  prep_all<<<dim3(2114), blk256, 0, stream>>>(
      src_h, dst_h, Wq, Wk, Wv, W1, W2, Wm, b1, bm,
      src_bf, dst_bf, Wqb, Wkv, Wf, W2b, b1p, st,
      total_src * H_DIM, total_dst * H_DIM);

  // 2: Q + fused K/V projections (64x128 tiles, counted vmcnt, XCD-swz)
  gemm_qkv<<<dim3(mbd * 4 + mbs * 8), blk256, 0, stream>>>(
      dst_bf, src_bf, Wqb, Wkv, bq, bk, bv, Qh, Kh, Vt, total_dst, total_src);

  // 3: attention -> Ob (bf16 [M,512] head-major)
  attn_v6<<<dim3(NBATCH, N_HEADS, 8), blk256, 0, stream>>>(
      Qh, Kh, Vt, d_lens, s_lens, Ob, total_dst, total_src);

  // 4: FFN1 (merge folded in): [dst_bf | Ob] @ Wf^T + b1p -> X1 + BN1 stats
  gemm_ffn<<<dim3(mbd * 4), blk256, 0, stream>>>(
      dst_bf, Ob, Wf, b1p, X1, st1, total_dst, 1024);

  // 5: FFN2 with fused BN1+ReLU on A: BN1(X1) @ W2b^T + b2 -> X2 + BN2 stats
  gemm_ffn2bn<<<dim3(mbd * 4), blk256, 0, stream>>>(
      X1, W2b, st1, g1, be1, b2, X2, st2, total_dst, invM);

  // 6: BN2 + residual -> d_out (fp32, float4-vectorized)
  bn2_apply<<<dim3(512), blk256, 0, stream>>>(
      X2, st2, g2, be2, dst_h, (float*)d_out, total_dst, invM);
}